// Round 2
// baseline (270.274 us; speedup 1.0000x reference)
//
#include <hip/hip_runtime.h>

#define NPTS 32768
#define BLOCK 256
#define SPT 16                            // source points per thread (packed coords ~5 VGPR/pt)
#define NSLICE 64                         // target slices per direction
#define SLICE_PTS (NPTS / NSLICE)         // 512
#define SRC_PER_BLOCK (BLOCK * SPT)       // 4096
#define SRC_CHUNKS (NPTS / SRC_PER_BLOCK) // 8
// grid = 2 * SRC_CHUNKS * NSLICE = 1024 blocks -> exactly 4 blocks/CU resident, 16 waves/CU

typedef float f32x2 __attribute__((ext_vector_type(2)));

// Pass 1: min_t |s-t|^2 = |s|^2 - 2 * max_t (s.t - |t|^2/2).
// LDS pair layout per 2 targets: {tx0,tx1,ty0,ty1 | tz0,tz1,qh0,qh1} so two
// ds_read_b128 yield aligned 64-bit operand pairs for v_pk_fma_f32.
// Inner step per point per 2 targets: 3 v_pk_fma_f32 + 1 v_max3_f32
// (2.06 instr/pair vs 3.5 scalar) -- tests the issue-bound hypothesis.
__global__ __launch_bounds__(BLOCK, 4)
void chamfer_pass1(const float* __restrict__ pred,
                   const float* __restrict__ targ,
                   unsigned int* __restrict__ mins) {
    __shared__ float4 sh[SLICE_PTS + 2];   // pair layout; +2 float4 = prefetch overrun pad

    int b = blockIdx.x;
    int dir = b / (SRC_CHUNKS * NSLICE);        // 0: pred->target, 1: target->pred
    int rem = b % (SRC_CHUNKS * NSLICE);
    int slice = rem / SRC_CHUNKS;               // 0..63
    int chunk = rem % SRC_CHUNKS;               // 0..7

    const float* src = dir ? targ : pred;
    const float* tgt = dir ? pred : targ;
    unsigned int* outm = mins + dir * NPTS;

    // stage target pair (2t, 2t+1): one pair per thread (256 pairs = 512 targets)
    {
        int t = threadIdx.x;
        int g = slice * SLICE_PTS + 2 * t;
        float x0 = tgt[3*g+0], y0 = tgt[3*g+1], z0 = tgt[3*g+2];
        float x1 = tgt[3*g+3], y1 = tgt[3*g+4], z1 = tgt[3*g+5];
        sh[2*t+0] = make_float4(x0, x1, y0, y1);
        sh[2*t+1] = make_float4(z0, z1,
                                -0.5f * (x0*x0 + y0*y0 + z0*z0),
                                -0.5f * (x1*x1 + y1*y1 + z1*z1));
    }

    // load 16 source points into packed register pairs
    f32x2 Pxy[SPT], Pzq[SPT];   // (sx,sy), (sz,|s|^2)
    float m[SPT];
    int i_base = chunk * SRC_PER_BLOCK + threadIdx.x;
    #pragma unroll
    for (int p = 0; p < SPT; ++p) {
        int i = i_base + p * BLOCK;
        float sx = src[3*i+0], sy = src[3*i+1], sz = src[3*i+2];
        Pxy[p] = (f32x2){sx, sy};
        Pzq[p] = (f32x2){sz, fmaf(sx, sx, fmaf(sy, sy, sz*sz))};
        m[p] = -3.4e38f;
    }
    __syncthreads();

    // software-pipelined over target pairs; pad makes last prefetch safe
    const f32x2* sh2 = (const f32x2*)sh;
    f32x2 TX = sh2[0], TY = sh2[1], TZ = sh2[2], QH = sh2[3];
    #pragma unroll 4
    for (int pp = 0; pp < SLICE_PTS / 2; ++pp) {
        f32x2 TXn = sh2[4*pp+4];
        f32x2 TYn = sh2[4*pp+5];
        f32x2 TZn = sh2[4*pp+6];
        f32x2 QHn = sh2[4*pp+7];
        #pragma unroll
        for (int p = 0; p < SPT; ++p) {
            f32x2 d;
            // d = sx*(tx0,tx1) + (qh0,qh1)      [broadcast Pxy.lo]
            asm("v_pk_fma_f32 %0, %1, %2, %3 op_sel:[0,0,0] op_sel_hi:[0,1,1]"
                : "=v"(d) : "v"(Pxy[p]), "v"(TX), "v"(QH));
            // d += sy*(ty0,ty1)                  [broadcast Pxy.hi]
            asm("v_pk_fma_f32 %0, %1, %2, %0 op_sel:[1,0,0] op_sel_hi:[1,1,1]"
                : "+v"(d) : "v"(Pxy[p]), "v"(TY));
            // d += sz*(tz0,tz1)                  [broadcast Pzq.lo]
            asm("v_pk_fma_f32 %0, %1, %2, %0 op_sel:[0,0,0] op_sel_hi:[0,1,1]"
                : "+v"(d) : "v"(Pzq[p]), "v"(TZ));
            m[p] = fmaxf(m[p], fmaxf(d.x, d.y));   // -> v_max3_f32
        }
        TX = TXn; TY = TYn; TZ = TZn; QH = QHn;
    }

    #pragma unroll
    for (int p = 0; p < SPT; ++p) {
        int i = i_base + p * BLOCK;
        float d = fmaxf(fmaf(-2.0f, m[p], Pzq[p].y), 0.0f);  // exact distance >= 0
        atomicMin(&outm[i], __float_as_uint(d));             // non-neg float: uint cmp ok
    }
}

// Pass 2: sum all 65536 per-point mins; out = sum / 32768 (= mean1 + mean2).
__global__ __launch_bounds__(256)
void chamfer_pass2(const unsigned int* __restrict__ mins,
                   float* __restrict__ out) {
    float sum = 0.0f;
    for (int i = blockIdx.x * blockDim.x + threadIdx.x; i < 2 * NPTS;
         i += gridDim.x * blockDim.x)
        sum += __uint_as_float(mins[i]);
    #pragma unroll
    for (int off = 32; off > 0; off >>= 1)
        sum += __shfl_down(sum, off, 64);
    __shared__ float wsum[4];
    int lane = threadIdx.x & 63, wave = threadIdx.x >> 6;
    if (lane == 0) wsum[wave] = sum;
    __syncthreads();
    if (threadIdx.x == 0) {
        float s = wsum[0] + wsum[1] + wsum[2] + wsum[3];
        atomicAdd(out, s * (1.0f / NPTS));
    }
}

extern "C" void kernel_launch(void* const* d_in, const int* in_sizes, int n_in,
                              void* d_out, int out_size, void* d_ws, size_t ws_size,
                              hipStream_t stream) {
    const float* pred = (const float*)d_in[0];
    const float* targ = (const float*)d_in[1];
    float* out = (float*)d_out;
    unsigned int* mins = (unsigned int*)d_ws;

    // sentinel 0x7F7F7F7F == 3.39e38f in every ws float
    hipMemsetAsync(d_ws, 0x7F, 2 * NPTS * sizeof(float), stream);
    hipMemsetAsync(d_out, 0, sizeof(float), stream);

    chamfer_pass1<<<2 * SRC_CHUNKS * NSLICE, BLOCK, 0, stream>>>(pred, targ, mins);
    chamfer_pass2<<<64, 256, 0, stream>>>(mins, out);
}